// Round 1
// baseline (858.801 us; speedup 1.0000x reference)
//
#include <hip/hip_runtime.h>

// GIN: 3 layers of {agg = scatter_sum(h[src] -> dst); h = relu(((1+eps)h + agg) @ W + b)}
// then per-graph segment-sum readout (graph_ids sorted) -> 2-layer MLP.
//
// Structure:
//  - Build dst-CSR once per call (hist -> single-block scan -> fill). Avoids
//    230M float atomics; costs ~2.4M int atomics + 1 tiny scan.
//  - Fused layer kernel: one wave per node. lane d holds dim d. Gather-sum
//    in-neighbor rows (256B contiguous each), then 64x64 matmul via
//    __shfl broadcast against LDS-staged W. No agg buffer materialized.
//  - Readout: 256 graphs x 16 splits, binary-search boundaries, partial sums,
//    one atomicAdd per thread per split into g[256,192].
//  - MLP: one block per graph.

#define SPLIT 16

__global__ void hist_kernel(const int* __restrict__ dst, int* __restrict__ deg, int E) {
    int i = blockIdx.x * blockDim.x + threadIdx.x;
    if (i < E) atomicAdd(&deg[dst[i]], 1);
}

__global__ __launch_bounds__(1024) void scan_kernel(const int* __restrict__ deg,
                                                    int* __restrict__ offsets, int N) {
    const int T = 1024;
    __shared__ int sh[T];
    int t = threadIdx.x;
    int C = (N + T - 1) / T;
    int base = t * C;
    int end = min(base + C, N);
    int s = 0;
    for (int i = base; i < end; ++i) s += deg[i];
    sh[t] = s;
    __syncthreads();
    for (int off = 1; off < T; off <<= 1) {
        int v = (t >= off) ? sh[t - off] : 0;
        __syncthreads();
        sh[t] += v;
        __syncthreads();
    }
    int excl = sh[t] - s;   // exclusive prefix of this thread's chunk
    int run = excl;
    for (int i = base; i < end; ++i) { offsets[i] = run; run += deg[i]; }
    if (t == T - 1) offsets[N] = run;  // last thread's range is empty or ends at N -> run == E
}

__global__ void fill_kernel(const int* __restrict__ src, const int* __restrict__ dst,
                            const int* __restrict__ offsets, int* __restrict__ cnt,
                            int* __restrict__ csr, int E) {
    int i = blockIdx.x * blockDim.x + threadIdx.x;
    if (i < E) {
        int d = dst[i];
        int pos = offsets[d] + atomicAdd(&cnt[d], 1);
        csr[pos] = src[i];
    }
}

// One wave per node. lane = dim. acc = (1+eps)*h[n][lane] + sum_{e in CSR(n)} h[src_e][lane]
// out[lane] = relu(b[lane] + sum_k shfl(acc,k) * W[k][lane])
__global__ __launch_bounds__(256) void gin_layer_kernel(
        const float* __restrict__ hin, float* __restrict__ hout,
        const int* __restrict__ offsets, const int* __restrict__ csr,
        const float* __restrict__ gin_W, const float* __restrict__ gin_b,
        const float* __restrict__ eps_arr, int layer, int N) {
    __shared__ float Ws[64 * 64];
    __shared__ float bs[64];
    const float* Wl = gin_W + layer * 4096;
    for (int i = threadIdx.x; i < 1024; i += 256)
        ((float4*)Ws)[i] = ((const float4*)Wl)[i];
    if (threadIdx.x < 64) bs[threadIdx.x] = gin_b[layer * 64 + threadIdx.x];
    float eps1 = 1.0f + eps_arr[layer];
    __syncthreads();

    int lane = threadIdx.x & 63;
    int wave = threadIdx.x >> 6;
    int n = blockIdx.x * 4 + wave;
    if (n >= N) return;

    float acc = eps1 * hin[(size_t)n * 64 + lane];
    int e0 = offsets[n], e1 = offsets[n + 1];
    for (int e = e0; e < e1; ++e) {
        int s = csr[e];                       // wave-uniform address
        acc += hin[(size_t)s * 64 + lane];    // 256B contiguous row
    }

    float out = bs[lane];
    #pragma unroll
    for (int k = 0; k < 64; ++k) {
        float bk = __shfl(acc, k, 64);
        out = fmaf(bk, Ws[k * 64 + lane], out);
    }
    out = fmaxf(out, 0.0f);
    hout[(size_t)n * 64 + lane] = out;
}

// 256 graphs x SPLIT splits; 192 threads (t = l*64+d); partial-sum then one atomicAdd.
__global__ __launch_bounds__(192) void readout_kernel(
        const float* __restrict__ H, const int* __restrict__ gids,
        float* __restrict__ g, int N) {
    int graph = blockIdx.x / SPLIT;
    int sp    = blockIdx.x % SPLIT;
    // lower_bound(graph), lower_bound(graph+1)
    int lo = 0, hi = N;
    while (lo < hi) { int mid = (lo + hi) >> 1; if (gids[mid] < graph) lo = mid + 1; else hi = mid; }
    int start = lo;
    int lo2 = start, hi2 = N;
    while (lo2 < hi2) { int mid = (lo2 + hi2) >> 1; if (gids[mid] < graph + 1) lo2 = mid + 1; else hi2 = mid; }
    int end = lo2;
    int cnt = end - start;
    if (cnt <= 0) return;
    int per = (cnt + SPLIT - 1) / SPLIT;
    int cs = start + sp * per;
    int ce = min(cs + per, end);
    if (cs >= ce) return;

    int t = threadIdx.x;            // 0..191
    int l = t >> 6, d = t & 63;
    const float* Hl = H + (size_t)l * N * 64;
    float acc = 0.0f;
    for (int n = cs; n < ce; ++n) acc += Hl[(size_t)n * 64 + d];
    atomicAdd(&g[graph * 192 + t], acc);
}

__global__ __launch_bounds__(192) void mlp_kernel(
        const float* __restrict__ g,
        const float* __restrict__ W1, const float* __restrict__ b1,
        const float* __restrict__ W2, const float* __restrict__ b2,
        float* __restrict__ out) {
    __shared__ float gr[192];
    __shared__ float hid[128];
    int graph = blockIdx.x;
    int t = threadIdx.x;
    gr[t] = g[graph * 192 + t];
    __syncthreads();
    if (t < 128) {
        float a = b1[t];
        for (int k = 0; k < 192; ++k) a = fmaf(gr[k], W1[k * 128 + t], a);
        hid[t] = fmaxf(a, 0.0f);
    }
    __syncthreads();
    if (t < 32) {
        float a = b2[t];
        for (int k = 0; k < 128; ++k) a = fmaf(hid[k], W2[k * 32 + t], a);
        out[graph * 32 + t] = a;
    }
}

extern "C" void kernel_launch(void* const* d_in, const int* in_sizes, int n_in,
                              void* d_out, int out_size, void* d_ws, size_t ws_size,
                              hipStream_t stream) {
    const float* x     = (const float*)d_in[0];
    const float* gin_W = (const float*)d_in[1];
    const float* gin_b = (const float*)d_in[2];
    const float* eps   = (const float*)d_in[3];
    const float* r_W1  = (const float*)d_in[4];
    const float* r_b1  = (const float*)d_in[5];
    const float* r_W2  = (const float*)d_in[6];
    const float* r_b2  = (const float*)d_in[7];
    const int*   src   = (const int*)d_in[8];
    const int*   dst   = (const int*)d_in[9];
    const int*   gids  = (const int*)d_in[10];

    int N = in_sizes[0] / 64;       // 100000
    int E = in_sizes[8];            // 1200000
    int B = out_size / 32;          // 256

    // workspace layout (4B words):
    //   deg[N] | cnt[N] | g[B*192]   <- zeroed region
    //   offsets[N+1] | csr[E] | H[3*N*64]
    int* ws       = (int*)d_ws;
    int* deg      = ws;
    int* cnt      = ws + N;
    float* g      = (float*)(ws + 2 * (size_t)N);
    int* offsets  = ws + 2 * (size_t)N + B * 192;
    int* csr      = offsets + (N + 1);
    float* H      = (float*)(csr + E);

    size_t zero_bytes = (2 * (size_t)N + (size_t)B * 192) * sizeof(int);
    hipMemsetAsync(d_ws, 0, zero_bytes, stream);

    int eb = (E + 255) / 256;
    hist_kernel<<<eb, 256, 0, stream>>>(dst, deg, E);
    scan_kernel<<<1, 1024, 0, stream>>>(deg, offsets, N);
    fill_kernel<<<eb, 256, 0, stream>>>(src, dst, offsets, cnt, csr, E);

    int nb = (N + 3) / 4;
    float* H0 = H;
    float* H1 = H + (size_t)N * 64;
    float* H2 = H + 2 * (size_t)N * 64;
    gin_layer_kernel<<<nb, 256, 0, stream>>>(x,  H0, offsets, csr, gin_W, gin_b, eps, 0, N);
    gin_layer_kernel<<<nb, 256, 0, stream>>>(H0, H1, offsets, csr, gin_W, gin_b, eps, 1, N);
    gin_layer_kernel<<<nb, 256, 0, stream>>>(H1, H2, offsets, csr, gin_W, gin_b, eps, 2, N);

    readout_kernel<<<B * SPLIT, 192, 0, stream>>>(H, gids, g, N);
    mlp_kernel<<<B, 192, 0, stream>>>(g, r_W1, r_b1, r_W2, r_b2, (float*)d_out);
}

// Round 2
// 770.840 us; speedup vs baseline: 1.1141x; 1.1141x over previous
//
#include <hip/hip_runtime.h>

// GIN: 3 layers of {agg = scatter_sum(h[src] -> dst); h = relu(((1+eps)h + agg) @ W + b)}
// then per-graph segment-sum readout (graph_ids sorted) -> 2-layer MLP.
//
// R2: gin_layer gather re-layout for memory-level parallelism.
//  - lane = group(2b) x float4-slot(4b): 16 lanes x float4 = one 256B row,
//    4 edges gathered per wave-instruction, unrolled x2 => 8 rows in flight.
//  - cross-group shfl_xor reduce, then shfl-broadcast 64x64 matmul vs LDS W.
// R1 was latency-bound: VALUBusy 19%, HBM 17.5%, 1 row in flight per wave.

#define SPLIT 16

__global__ void hist_kernel(const int* __restrict__ dst, int* __restrict__ deg, int E) {
    int i = blockIdx.x * blockDim.x + threadIdx.x;
    if (i < E) atomicAdd(&deg[dst[i]], 1);
}

__global__ __launch_bounds__(1024) void scan_kernel(const int* __restrict__ deg,
                                                    int* __restrict__ offsets, int N) {
    const int T = 1024;
    __shared__ int sh[T];
    int t = threadIdx.x;
    int C = (N + T - 1) / T;
    int base = t * C;
    int end = min(base + C, N);
    int s = 0;
    for (int i = base; i < end; ++i) s += deg[i];
    sh[t] = s;
    __syncthreads();
    for (int off = 1; off < T; off <<= 1) {
        int v = (t >= off) ? sh[t - off] : 0;
        __syncthreads();
        sh[t] += v;
        __syncthreads();
    }
    int excl = sh[t] - s;   // exclusive prefix of this thread's chunk
    int run = excl;
    for (int i = base; i < end; ++i) { offsets[i] = run; run += deg[i]; }
    if (t == T - 1) offsets[N] = run;
}

__global__ void fill_kernel(const int* __restrict__ src, const int* __restrict__ dst,
                            const int* __restrict__ offsets, int* __restrict__ cnt,
                            int* __restrict__ csr, int E) {
    int i = blockIdx.x * blockDim.x + threadIdx.x;
    if (i < E) {
        int d = dst[i];
        int pos = offsets[d] + atomicAdd(&cnt[d], 1);
        csr[pos] = src[i];
    }
}

// One wave per node. lane = g*16+sl. Group g handles edges e0+g, e0+g+4, ...
// Each lane loads float4 #sl of the 64-float row (16 lanes = full row).
__global__ __launch_bounds__(256) void gin_layer_kernel(
        const float* __restrict__ hin, float* __restrict__ hout,
        const int* __restrict__ offsets, const int* __restrict__ csr,
        const float* __restrict__ gin_W, const float* __restrict__ gin_b,
        const float* __restrict__ eps_arr, int layer, int N) {
    __shared__ float Ws[64 * 64];
    __shared__ float bs[64];
    const float* Wl = gin_W + layer * 4096;
    for (int i = threadIdx.x; i < 1024; i += 256)
        ((float4*)Ws)[i] = ((const float4*)Wl)[i];
    if (threadIdx.x < 64) bs[threadIdx.x] = gin_b[layer * 64 + threadIdx.x];
    float eps1 = 1.0f + eps_arr[layer];
    __syncthreads();

    int lane = threadIdx.x & 63;
    int wave = threadIdx.x >> 6;
    int n = blockIdx.x * 4 + wave;
    if (n >= N) return;

    int g  = lane >> 4;    // edge group 0..3
    int sl = lane & 15;    // float4 slot within row

    int e0 = offsets[n], e1 = offsets[n + 1];
    float ax = 0.f, ay = 0.f, az = 0.f, aw = 0.f;

    int e = e0 + g;
    for (; e + 4 < e1; e += 8) {           // both e and e+4 valid
        int s0 = csr[e];
        int s1 = csr[e + 4];
        float4 v0 = ((const float4*)(hin + (size_t)s0 * 64))[sl];
        float4 v1 = ((const float4*)(hin + (size_t)s1 * 64))[sl];
        ax += v0.x; ay += v0.y; az += v0.z; aw += v0.w;
        ax += v1.x; ay += v1.y; az += v1.z; aw += v1.w;
    }
    if (e < e1) {
        int s0 = csr[e];
        float4 v0 = ((const float4*)(hin + (size_t)s0 * 64))[sl];
        ax += v0.x; ay += v0.y; az += v0.z; aw += v0.w;
    }

    // reduce across the 4 groups (lanes sl, sl+16, sl+32, sl+48)
    ax += __shfl_xor(ax, 16, 64); ax += __shfl_xor(ax, 32, 64);
    ay += __shfl_xor(ay, 16, 64); ay += __shfl_xor(ay, 32, 64);
    az += __shfl_xor(az, 16, 64); az += __shfl_xor(az, 32, 64);
    aw += __shfl_xor(aw, 16, 64); aw += __shfl_xor(aw, 32, 64);

    // self term (replicated across groups, consistent)
    float4 self = ((const float4*)(hin + (size_t)n * 64))[sl];
    ax = fmaf(eps1, self.x, ax);
    ay = fmaf(eps1, self.y, ay);
    az = fmaf(eps1, self.z, az);
    aw = fmaf(eps1, self.w, aw);

    // matmul: out[lane] = b[lane] + sum_k acc[k] * Ws[k][lane]
    // acc[4*k'+j] lives in component j of lane k' (k' < 16, replicated in all groups)
    float out = bs[lane];
    #pragma unroll
    for (int k = 0; k < 16; ++k) {
        float b0 = __shfl(ax, k, 64);
        float b1 = __shfl(ay, k, 64);
        float b2 = __shfl(az, k, 64);
        float b3 = __shfl(aw, k, 64);
        out = fmaf(b0, Ws[(4 * k + 0) * 64 + lane], out);
        out = fmaf(b1, Ws[(4 * k + 1) * 64 + lane], out);
        out = fmaf(b2, Ws[(4 * k + 2) * 64 + lane], out);
        out = fmaf(b3, Ws[(4 * k + 3) * 64 + lane], out);
    }
    out = fmaxf(out, 0.0f);
    hout[(size_t)n * 64 + lane] = out;
}

// 256 graphs x SPLIT splits; 192 threads (t = l*64+d); partial-sum then one atomicAdd.
__global__ __launch_bounds__(192) void readout_kernel(
        const float* __restrict__ H, const int* __restrict__ gids,
        float* __restrict__ g, int N) {
    int graph = blockIdx.x / SPLIT;
    int sp    = blockIdx.x % SPLIT;
    int lo = 0, hi = N;
    while (lo < hi) { int mid = (lo + hi) >> 1; if (gids[mid] < graph) lo = mid + 1; else hi = mid; }
    int start = lo;
    int lo2 = start, hi2 = N;
    while (lo2 < hi2) { int mid = (lo2 + hi2) >> 1; if (gids[mid] < graph + 1) lo2 = mid + 1; else hi2 = mid; }
    int end = lo2;
    int cnt = end - start;
    if (cnt <= 0) return;
    int per = (cnt + SPLIT - 1) / SPLIT;
    int cs = start + sp * per;
    int ce = min(cs + per, end);
    if (cs >= ce) return;

    int t = threadIdx.x;            // 0..191
    int l = t >> 6, d = t & 63;
    const float* Hl = H + (size_t)l * N * 64;
    float acc = 0.0f;
    for (int n = cs; n < ce; ++n) acc += Hl[(size_t)n * 64 + d];
    atomicAdd(&g[graph * 192 + t], acc);
}

__global__ __launch_bounds__(192) void mlp_kernel(
        const float* __restrict__ g,
        const float* __restrict__ W1, const float* __restrict__ b1,
        const float* __restrict__ W2, const float* __restrict__ b2,
        float* __restrict__ out) {
    __shared__ float gr[192];
    __shared__ float hid[128];
    int graph = blockIdx.x;
    int t = threadIdx.x;
    gr[t] = g[graph * 192 + t];
    __syncthreads();
    if (t < 128) {
        float a = b1[t];
        for (int k = 0; k < 192; ++k) a = fmaf(gr[k], W1[k * 128 + t], a);
        hid[t] = fmaxf(a, 0.0f);
    }
    __syncthreads();
    if (t < 32) {
        float a = b2[t];
        for (int k = 0; k < 128; ++k) a = fmaf(hid[k], W2[k * 32 + t], a);
        out[graph * 32 + t] = a;
    }
}

extern "C" void kernel_launch(void* const* d_in, const int* in_sizes, int n_in,
                              void* d_out, int out_size, void* d_ws, size_t ws_size,
                              hipStream_t stream) {
    const float* x     = (const float*)d_in[0];
    const float* gin_W = (const float*)d_in[1];
    const float* gin_b = (const float*)d_in[2];
    const float* eps   = (const float*)d_in[3];
    const float* r_W1  = (const float*)d_in[4];
    const float* r_b1  = (const float*)d_in[5];
    const float* r_W2  = (const float*)d_in[6];
    const float* r_b2  = (const float*)d_in[7];
    const int*   src   = (const int*)d_in[8];
    const int*   dst   = (const int*)d_in[9];
    const int*   gids  = (const int*)d_in[10];

    int N = in_sizes[0] / 64;       // 100000
    int E = in_sizes[8];            // 1200000
    int B = out_size / 32;          // 256

    // workspace layout (4B words):
    //   deg[N] | cnt[N] | g[B*192]   <- zeroed region
    //   offsets[N+1] | csr[E] | H[3*N*64]
    int* ws       = (int*)d_ws;
    int* deg      = ws;
    int* cnt      = ws + N;
    float* g      = (float*)(ws + 2 * (size_t)N);
    int* offsets  = ws + 2 * (size_t)N + B * 192;
    int* csr      = offsets + (N + 1);
    float* H      = (float*)(csr + E);

    size_t zero_bytes = (2 * (size_t)N + (size_t)B * 192) * sizeof(int);
    hipMemsetAsync(d_ws, 0, zero_bytes, stream);

    int eb = (E + 255) / 256;
    hist_kernel<<<eb, 256, 0, stream>>>(dst, deg, E);
    scan_kernel<<<1, 1024, 0, stream>>>(deg, offsets, N);
    fill_kernel<<<eb, 256, 0, stream>>>(src, dst, offsets, cnt, csr, E);

    int nb = (N + 3) / 4;
    float* H0 = H;
    float* H1 = H + (size_t)N * 64;
    float* H2 = H + 2 * (size_t)N * 64;
    gin_layer_kernel<<<nb, 256, 0, stream>>>(x,  H0, offsets, csr, gin_W, gin_b, eps, 0, N);
    gin_layer_kernel<<<nb, 256, 0, stream>>>(H0, H1, offsets, csr, gin_W, gin_b, eps, 1, N);
    gin_layer_kernel<<<nb, 256, 0, stream>>>(H1, H2, offsets, csr, gin_W, gin_b, eps, 2, N);

    readout_kernel<<<B * SPLIT, 192, 0, stream>>>(H, gids, g, N);
    mlp_kernel<<<B, 192, 0, stream>>>(g, r_W1, r_b1, r_W2, r_b2, (float*)d_out);
}

// Round 3
// 604.845 us; speedup vs baseline: 1.4199x; 1.2744x over previous
//
#include <hip/hip_runtime.h>

// GIN: 3 layers of {agg = scatter_sum(h[src] -> dst); h = relu(((1+eps)h + agg) @ W + b)}
// then per-graph segment-sum readout (graph_ids sorted) -> 2-layer MLP.
//
// R3: replace the single-block O(161us) scan with a 3-kernel parallel scan
//     (partial-reduce -> mid-scan -> final-scatter), each pass fully parallel.
// R2: gather re-layout (4 edges/wave-load via lane=group x float4-slot): done.

#define SPLIT 16

__global__ void hist_kernel(const int* __restrict__ dst, int* __restrict__ deg, int E) {
    int i = blockIdx.x * blockDim.x + threadIdx.x;
    if (i < E) atomicAdd(&deg[dst[i]], 1);
}

// --- 3-phase parallel scan over deg[N] -> offsets[N+1] ---
// thread i covers elements 2i, 2i+1. 256 threads/block -> 512 elems/block.

__global__ __launch_bounds__(256) void scan_part_kernel(const int* __restrict__ deg,
                                                        int* __restrict__ bsum, int N) {
    __shared__ int sh[256];
    int t = threadIdx.x;
    int i = (blockIdx.x * 256 + t) * 2;
    int s = 0;
    if (i < N) s += deg[i];
    if (i + 1 < N) s += deg[i + 1];
    sh[t] = s;
    __syncthreads();
    for (int off = 128; off > 0; off >>= 1) {
        if (t < off) sh[t] += sh[t + off];
        __syncthreads();
    }
    if (t == 0) bsum[blockIdx.x] = sh[0];
}

__global__ __launch_bounds__(256) void scan_mid_kernel(const int* __restrict__ bsum,
                                                       int* __restrict__ boff, int nb) {
    __shared__ int sh[256];
    int t = threadIdx.x;
    int v = (t < nb) ? bsum[t] : 0;
    sh[t] = v;
    __syncthreads();
    for (int off = 1; off < 256; off <<= 1) {
        int u = (t >= off) ? sh[t - off] : 0;
        __syncthreads();
        sh[t] += u;
        __syncthreads();
    }
    if (t < nb) boff[t] = sh[t] - v;   // exclusive prefix of block sums
}

__global__ __launch_bounds__(256) void scan_final_kernel(const int* __restrict__ deg,
                                                         const int* __restrict__ boff,
                                                         int* __restrict__ offsets,
                                                         int N, int E) {
    __shared__ int sh[256];
    int t = threadIdx.x;
    int i = (blockIdx.x * 256 + t) * 2;
    int d0 = (i < N) ? deg[i] : 0;
    int d1 = (i + 1 < N) ? deg[i + 1] : 0;
    int s = d0 + d1;
    sh[t] = s;
    __syncthreads();
    for (int off = 1; off < 256; off <<= 1) {
        int u = (t >= off) ? sh[t - off] : 0;
        __syncthreads();
        sh[t] += u;
        __syncthreads();
    }
    int pre = boff[blockIdx.x] + sh[t] - s;   // exclusive prefix of element i
    if (i < N) offsets[i] = pre;
    if (i + 1 < N) offsets[i + 1] = pre + d0;
    if (blockIdx.x == 0 && t == 0) offsets[N] = E;
}

__global__ void fill_kernel(const int* __restrict__ src, const int* __restrict__ dst,
                            const int* __restrict__ offsets, int* __restrict__ cnt,
                            int* __restrict__ csr, int E) {
    int i = blockIdx.x * blockDim.x + threadIdx.x;
    if (i < E) {
        int d = dst[i];
        int pos = offsets[d] + atomicAdd(&cnt[d], 1);
        csr[pos] = src[i];
    }
}

// One wave per node. lane = g*16+sl. Group g handles edges e0+g, e0+g+4, ...
// Each lane loads float4 #sl of the 64-float row (16 lanes = full row).
__global__ __launch_bounds__(256) void gin_layer_kernel(
        const float* __restrict__ hin, float* __restrict__ hout,
        const int* __restrict__ offsets, const int* __restrict__ csr,
        const float* __restrict__ gin_W, const float* __restrict__ gin_b,
        const float* __restrict__ eps_arr, int layer, int N) {
    __shared__ float Ws[64 * 64];
    __shared__ float bs[64];
    const float* Wl = gin_W + layer * 4096;
    for (int i = threadIdx.x; i < 1024; i += 256)
        ((float4*)Ws)[i] = ((const float4*)Wl)[i];
    if (threadIdx.x < 64) bs[threadIdx.x] = gin_b[layer * 64 + threadIdx.x];
    float eps1 = 1.0f + eps_arr[layer];
    __syncthreads();

    int lane = threadIdx.x & 63;
    int wave = threadIdx.x >> 6;
    int n = blockIdx.x * 4 + wave;
    if (n >= N) return;

    int g  = lane >> 4;    // edge group 0..3
    int sl = lane & 15;    // float4 slot within row

    int e0 = offsets[n], e1 = offsets[n + 1];
    float ax = 0.f, ay = 0.f, az = 0.f, aw = 0.f;

    int e = e0 + g;
    for (; e + 4 < e1; e += 8) {           // both e and e+4 valid
        int s0 = csr[e];
        int s1 = csr[e + 4];
        float4 v0 = ((const float4*)(hin + (size_t)s0 * 64))[sl];
        float4 v1 = ((const float4*)(hin + (size_t)s1 * 64))[sl];
        ax += v0.x; ay += v0.y; az += v0.z; aw += v0.w;
        ax += v1.x; ay += v1.y; az += v1.z; aw += v1.w;
    }
    if (e < e1) {
        int s0 = csr[e];
        float4 v0 = ((const float4*)(hin + (size_t)s0 * 64))[sl];
        ax += v0.x; ay += v0.y; az += v0.z; aw += v0.w;
    }

    // reduce across the 4 groups (lanes sl, sl+16, sl+32, sl+48)
    ax += __shfl_xor(ax, 16, 64); ax += __shfl_xor(ax, 32, 64);
    ay += __shfl_xor(ay, 16, 64); ay += __shfl_xor(ay, 32, 64);
    az += __shfl_xor(az, 16, 64); az += __shfl_xor(az, 32, 64);
    aw += __shfl_xor(aw, 16, 64); aw += __shfl_xor(aw, 32, 64);

    // self term (replicated across groups, consistent)
    float4 self = ((const float4*)(hin + (size_t)n * 64))[sl];
    ax = fmaf(eps1, self.x, ax);
    ay = fmaf(eps1, self.y, ay);
    az = fmaf(eps1, self.z, az);
    aw = fmaf(eps1, self.w, aw);

    // matmul: out[lane] = b[lane] + sum_k acc[k] * Ws[k][lane]
    // acc[4*k'+j] lives in component j of lane k' (k' < 16, replicated in all groups)
    float out = bs[lane];
    #pragma unroll
    for (int k = 0; k < 16; ++k) {
        float b0 = __shfl(ax, k, 64);
        float b1 = __shfl(ay, k, 64);
        float b2 = __shfl(az, k, 64);
        float b3 = __shfl(aw, k, 64);
        out = fmaf(b0, Ws[(4 * k + 0) * 64 + lane], out);
        out = fmaf(b1, Ws[(4 * k + 1) * 64 + lane], out);
        out = fmaf(b2, Ws[(4 * k + 2) * 64 + lane], out);
        out = fmaf(b3, Ws[(4 * k + 3) * 64 + lane], out);
    }
    out = fmaxf(out, 0.0f);
    hout[(size_t)n * 64 + lane] = out;
}

// 256 graphs x SPLIT splits; 192 threads (t = l*64+d); partial-sum then one atomicAdd.
__global__ __launch_bounds__(192) void readout_kernel(
        const float* __restrict__ H, const int* __restrict__ gids,
        float* __restrict__ g, int N) {
    int graph = blockIdx.x / SPLIT;
    int sp    = blockIdx.x % SPLIT;
    int lo = 0, hi = N;
    while (lo < hi) { int mid = (lo + hi) >> 1; if (gids[mid] < graph) lo = mid + 1; else hi = mid; }
    int start = lo;
    int lo2 = start, hi2 = N;
    while (lo2 < hi2) { int mid = (lo2 + hi2) >> 1; if (gids[mid] < graph + 1) lo2 = mid + 1; else hi2 = mid; }
    int end = lo2;
    int cnt = end - start;
    if (cnt <= 0) return;
    int per = (cnt + SPLIT - 1) / SPLIT;
    int cs = start + sp * per;
    int ce = min(cs + per, end);
    if (cs >= ce) return;

    int t = threadIdx.x;            // 0..191
    int l = t >> 6, d = t & 63;
    const float* Hl = H + (size_t)l * N * 64;
    float acc = 0.0f;
    for (int n = cs; n < ce; ++n) acc += Hl[(size_t)n * 64 + d];
    atomicAdd(&g[graph * 192 + t], acc);
}

__global__ __launch_bounds__(192) void mlp_kernel(
        const float* __restrict__ g,
        const float* __restrict__ W1, const float* __restrict__ b1,
        const float* __restrict__ W2, const float* __restrict__ b2,
        float* __restrict__ out) {
    __shared__ float gr[192];
    __shared__ float hid[128];
    int graph = blockIdx.x;
    int t = threadIdx.x;
    gr[t] = g[graph * 192 + t];
    __syncthreads();
    if (t < 128) {
        float a = b1[t];
        for (int k = 0; k < 192; ++k) a = fmaf(gr[k], W1[k * 128 + t], a);
        hid[t] = fmaxf(a, 0.0f);
    }
    __syncthreads();
    if (t < 32) {
        float a = b2[t];
        for (int k = 0; k < 128; ++k) a = fmaf(hid[k], W2[k * 32 + t], a);
        out[graph * 32 + t] = a;
    }
}

extern "C" void kernel_launch(void* const* d_in, const int* in_sizes, int n_in,
                              void* d_out, int out_size, void* d_ws, size_t ws_size,
                              hipStream_t stream) {
    const float* x     = (const float*)d_in[0];
    const float* gin_W = (const float*)d_in[1];
    const float* gin_b = (const float*)d_in[2];
    const float* eps   = (const float*)d_in[3];
    const float* r_W1  = (const float*)d_in[4];
    const float* r_b1  = (const float*)d_in[5];
    const float* r_W2  = (const float*)d_in[6];
    const float* r_b2  = (const float*)d_in[7];
    const int*   src   = (const int*)d_in[8];
    const int*   dst   = (const int*)d_in[9];
    const int*   gids  = (const int*)d_in[10];

    int N = in_sizes[0] / 64;       // 100000
    int E = in_sizes[8];            // 1200000
    int B = out_size / 32;          // 256

    // workspace layout (4B words):
    //   deg[N] | cnt[N] | g[B*192]   <- zeroed region
    //   offsets[N+1] | csr[E] | bsum[nb] | boff[nb] | H[3*N*64]
    int nb_scan = (N + 511) / 512;  // 196 for N=100000 (must be <= 256)
    int* ws       = (int*)d_ws;
    int* deg      = ws;
    int* cnt      = ws + N;
    float* g      = (float*)(ws + 2 * (size_t)N);
    int* offsets  = ws + 2 * (size_t)N + B * 192;
    int* csr      = offsets + (N + 1);
    int* bsum     = csr + E;
    int* boff     = bsum + nb_scan;
    float* H      = (float*)(boff + nb_scan);

    size_t zero_bytes = (2 * (size_t)N + (size_t)B * 192) * sizeof(int);
    hipMemsetAsync(d_ws, 0, zero_bytes, stream);

    int eb = (E + 255) / 256;
    hist_kernel<<<eb, 256, 0, stream>>>(dst, deg, E);
    scan_part_kernel<<<nb_scan, 256, 0, stream>>>(deg, bsum, N);
    scan_mid_kernel<<<1, 256, 0, stream>>>(bsum, boff, nb_scan);
    scan_final_kernel<<<nb_scan, 256, 0, stream>>>(deg, boff, offsets, N, E);
    fill_kernel<<<eb, 256, 0, stream>>>(src, dst, offsets, cnt, csr, E);

    int nbk = (N + 3) / 4;
    float* H0 = H;
    float* H1 = H + (size_t)N * 64;
    float* H2 = H + 2 * (size_t)N * 64;
    gin_layer_kernel<<<nbk, 256, 0, stream>>>(x,  H0, offsets, csr, gin_W, gin_b, eps, 0, N);
    gin_layer_kernel<<<nbk, 256, 0, stream>>>(H0, H1, offsets, csr, gin_W, gin_b, eps, 1, N);
    gin_layer_kernel<<<nbk, 256, 0, stream>>>(H1, H2, offsets, csr, gin_W, gin_b, eps, 2, N);

    readout_kernel<<<B * SPLIT, 192, 0, stream>>>(H, gids, g, N);
    mlp_kernel<<<B, 192, 0, stream>>>(g, r_W1, r_b1, r_W2, r_b2, (float*)d_out);
}